// Round 11
// baseline (129.968 us; speedup 1.0000x reference)
//
#include <hip/hip_runtime.h>
#include <hip/hip_bf16.h>

#define NROWS 12288
#define NDIM  128
#define HID   16

#define NJC    16                // j-chunks (partials)
#define JSPAN  (NROWS / NJC)     // 768
#define JSTEPS (JSPAN / 32)      // 24

typedef float f32x16 __attribute__((ext_vector_type(16)));
typedef short s16x8  __attribute__((ext_vector_type(8)));

// Module-level scratch (BSS): fully rewritten every call; no d_ws dependence.
__device__ __align__(16) ushort g_hb [NROWS * HID];        // bf16 H
__device__ __align__(16) ushort g_hbs[NROWS * HID];        // bf16 (H * log2e)  (QK^T j-side)
__device__ __align__(16) ushort g_hbT[17 * NROWS];         // bf16 H^T, row 16 = ones (denominator)
__device__ float g_pout[(size_t)NJC * NROWS * 17];         // PV partials: 16 num + 1 den per row

__device__ __forceinline__ ushort f2bf(float f) {          // RNE f32->bf16
    union { float f; unsigned u; } v; v.f = f;
    unsigned r = v.u + 0x7fffu + ((v.u >> 16) & 1u);
    return (ushort)(r >> 16);
}

__device__ __forceinline__ float fast_exp2(float x) {
#if __has_builtin(__builtin_amdgcn_exp2f)
    return __builtin_amdgcn_exp2f(x);
#else
    return exp2f(x);
#endif
}

// Pack two f32 -> one uint of 2 bf16 (RNE), p0 in low half (same as
// v_cvt_pk_bf16_f32). Header intrinsic: compiler-visible, no inline asm.
__device__ __forceinline__ uint pack_bf16(float p0, float p1) {
    union { __hip_bfloat162 h2; uint u; } cv;
    cv.h2 = __float22bfloat162_rn(make_float2(p0, p1));
    return cv.u;
}

// Functional equivalent of v_permlane32_swap_b32(x, y): exchange x's upper
// 32 lanes with y's lower 32 lanes. Pure shfl+select, no inline asm.
// FORENSIC NOTE (r6/r7/r8/r10 failures, absmax ~0.4; r7 failed with a body
// line-identical to passing r5 — allocation context, not code shape): raw
// v_permlane32_swap/v_cvt_pk inline asm is context-fragile on this compiler.
// NEVER reintroduce inline asm for the pack/swap path.
__device__ __forceinline__ void half_swap(uint& x, uint& y, bool up) {
    const uint xs = __shfl_xor(x, 32, 64);
    const uint ys = __shfl_xor(y, 32, 64);
    const uint nx = up ? ys : x;
    const uint ny = up ? y : xs;
    x = nx; y = ny;
}

// ---------------------------------------------------------------------------
// Kernel A: MLP -> bf16 H, bf16 H*log2e, bf16 H^T (+ ones row).
// Round-9 version verbatim (known good).
// ---------------------------------------------------------------------------
__global__ __launch_bounds__(64) void mlp_kernel(
    const float* __restrict__ x,
    const float* __restrict__ W1, const float* __restrict__ b1,
    const float* __restrict__ W2, const float* __restrict__ b2,
    const float* __restrict__ W3, const float* __restrict__ b3)
{
    __shared__ float sW1[NDIM * HID];
    __shared__ float sW2[HID * HID];
    __shared__ float sW3[HID * HID];
    __shared__ float sb[3 * HID];

    const int t = threadIdx.x;
    for (int i = t; i < NDIM * HID; i += 64) sW1[i] = W1[i];
    for (int i = t; i < HID * HID; i += 64) { sW2[i] = W2[i]; sW3[i] = W3[i]; }
    if (t < HID) { sb[t] = b1[t]; sb[HID + t] = b2[t]; sb[2 * HID + t] = b3[t]; }
    __syncthreads();

    const int row = blockIdx.x * 64 + t;
    if (row >= NROWS) return;

    float a1[HID];
    #pragma unroll
    for (int c = 0; c < HID; ++c) a1[c] = sb[c];
    const float4* xr = reinterpret_cast<const float4*>(x + (size_t)row * NDIM);
    #pragma unroll 8
    for (int k4 = 0; k4 < NDIM / 4; ++k4) {
        float4 v = xr[k4];
        const float* w0 = &sW1[(k4 * 4 + 0) * HID];
        const float* w1 = &sW1[(k4 * 4 + 1) * HID];
        const float* w2 = &sW1[(k4 * 4 + 2) * HID];
        const float* w3 = &sW1[(k4 * 4 + 3) * HID];
        #pragma unroll
        for (int c = 0; c < HID; ++c)
            a1[c] += v.x * w0[c] + v.y * w1[c] + v.z * w2[c] + v.w * w3[c];
    }

    float a2[HID];
    #pragma unroll
    for (int c = 0; c < HID; ++c) a2[c] = sb[HID + c];
    #pragma unroll
    for (int k = 0; k < HID; ++k) {
        const float hk = a1[k];
        #pragma unroll
        for (int c = 0; c < HID; ++c) a2[c] += hk * sW2[k * HID + c];
    }

    float a3[HID];
    #pragma unroll
    for (int c = 0; c < HID; ++c) a3[c] = sb[2 * HID + c];
    #pragma unroll
    for (int k = 0; k < HID; ++k) {
        const float hk = a2[k];
        #pragma unroll
        for (int c = 0; c < HID; ++c) a3[c] += hk * sW3[k * HID + c];
    }

    ushort hb[HID], hs[HID];
    #pragma unroll
    for (int c = 0; c < HID; ++c) {
        hb[c] = f2bf(a3[c]);
        hs[c] = f2bf(a3[c] * 1.44269504088896f);   // * log2(e)
    }
    uint wb[8], ws[8];
    #pragma unroll
    for (int d = 0; d < 8; ++d) {
        wb[d] = (uint)hb[2 * d] | ((uint)hb[2 * d + 1] << 16);
        ws[d] = (uint)hs[2 * d] | ((uint)hs[2 * d + 1] << 16);
    }
    uint4* pb = reinterpret_cast<uint4*>(g_hb  + (size_t)row * HID);
    uint4* ps = reinterpret_cast<uint4*>(g_hbs + (size_t)row * HID);
    pb[0] = make_uint4(wb[0], wb[1], wb[2], wb[3]);
    pb[1] = make_uint4(wb[4], wb[5], wb[6], wb[7]);
    ps[0] = make_uint4(ws[0], ws[1], ws[2], ws[3]);
    ps[1] = make_uint4(ws[4], ws[5], ws[6], ws[7]);
    #pragma unroll
    for (int c = 0; c < HID; ++c) g_hbT[(size_t)c * NROWS + row] = hb[c];
    g_hbT[(size_t)16 * NROWS + row] = 0x3F80;      // bf16(1.0): denominator column
}

// ---------------------------------------------------------------------------
// Kernel B: MFMA flash aggregation. Round-9 structure; ONE change: the
// pack/swap path uses header intrinsics + shfl (zero inline asm in this
// kernel). INVARIANT: no min-waves arg on launch_bounds; no inline asm.
// Wave: 32 i-rows. Per 32-j step:
//   S^T[j][i] = mfma_32x32x16(A=Hs[j-rows], B=H[i-rows], 0)   (K=HID=16)
//   p = exp2(S>0 ? S : -200)  (16 f32/lane)
//   pack_bf16 pairs + half_swap -> two K=16 bf16 A-frags of P[i][j]
//   acc = mfma(P1, HT[j..j+15], acc); acc = mfma(P2, HT[j+16..j+31], acc)
// B-side col 16 is all-ones => acc col 16 = sum_j p = denominator (free).
// ---------------------------------------------------------------------------
__global__ __launch_bounds__(256) void agg_kernel()
{
    const int lane = threadIdx.x & 63;
    const int wv   = threadIdx.x >> 6;
    const int jl   = lane & 31;       // row-in-tile for frag loads
    const int kh   = lane >> 5;       // k-half selector
    const bool up  = (lane >= 32);
    const int i0   = blockIdx.x * 128 + wv * 32;
    const int q    = blockIdx.y;
    const int jbase = q * JSPAN;

    // i-side B frag (unscaled H rows i0..i0+31), loaded once
    const s16x8 bi = *reinterpret_cast<const s16x8*>(&g_hb[((size_t)(i0 + jl)) * HID + kh * 8]);
    // PV B-side column base; cols >16 clamp to the ones-column (unused output)
    const int ccol = lane & 31;
    const ushort* tcol = &g_hbT[(size_t)(ccol < 16 ? ccol : 16) * NROWS];

    f32x16 acc, z;
    #pragma unroll
    for (int r = 0; r < 16; ++r) { acc[r] = 0.0f; z[r] = 0.0f; }

    for (int js = 0; js < JSTEPS; ++js) {
        const int j0 = jbase + js * 32;

        const s16x8 aj = *reinterpret_cast<const s16x8*>(&g_hbs[((size_t)(j0 + jl)) * HID + kh * 8]);
        f32x16 S = __builtin_amdgcn_mfma_f32_32x32x16_bf16(aj, bi, z, 0, 0, 0);

        float p[16];
        #pragma unroll
        for (int r = 0; r < 16; ++r) {
            const float s   = S[r];
            const float sel = (s > 0.0f) ? s : -200.0f;   // exp2(-200)=0 => strict mask
            p[r] = fast_exp2(sel);
        }

        // ---- chunk 1: j0..j0+15 (C regs 0..7) ----
        uint qa = pack_bf16(p[0], p[1]);
        uint qb = pack_bf16(p[2], p[3]);
        uint qc = pack_bf16(p[4], p[5]);
        uint qd = pack_bf16(p[6], p[7]);
        half_swap(qa, qc, up);
        half_swap(qb, qd, up);
        union { uint u[4]; s16x8 v; } A1;
        A1.u[0] = qa; A1.u[1] = qb; A1.u[2] = qc; A1.u[3] = qd;

        // ---- chunk 2: j0+16..j0+31 (C regs 8..15) ----
        uint qe = pack_bf16(p[8],  p[9]);
        uint qf = pack_bf16(p[10], p[11]);
        uint qg = pack_bf16(p[12], p[13]);
        uint qh = pack_bf16(p[14], p[15]);
        half_swap(qe, qg, up);
        half_swap(qf, qh, up);
        union { uint u[4]; s16x8 v; } A2;
        A2.u[0] = qe; A2.u[1] = qf; A2.u[2] = qg; A2.u[3] = qh;

        const s16x8 b1 = *reinterpret_cast<const s16x8*>(&tcol[j0 + kh * 8]);
        const s16x8 b2 = *reinterpret_cast<const s16x8*>(&tcol[j0 + 16 + kh * 8]);

        acc = __builtin_amdgcn_mfma_f32_32x32x16_bf16(A1.v, b1, acc, 0, 0, 0);
        acc = __builtin_amdgcn_mfma_f32_32x32x16_bf16(A2.v, b2, acc, 0, 0, 0);
    }

    // PV output tile: col c = lane&31 (c<=16 valid incl. den), row i = (r&3)+8*(r>>2)+4*kh
    if (ccol < 17) {
        #pragma unroll
        for (int r = 0; r < 16; ++r) {
            const int il = (r & 3) + 8 * (r >> 2) + 4 * kh;
            g_pout[((size_t)q * NROWS + (i0 + il)) * 17 + ccol] = acc[r];
        }
    }
}

// ---------------------------------------------------------------------------
// Kernel C: merge partials; out = log_softmax(num/den). 16 lanes per row.
// ---------------------------------------------------------------------------
__global__ __launch_bounds__(256) void finalize_kernel(float* __restrict__ out)
{
    const int gid = blockIdx.x * 256 + threadIdx.x;
    const int row = gid >> 4;
    const int c   = gid & 15;
    if (row >= NROWS) return;

    float num = 0.0f, den = 0.0f;
    #pragma unroll
    for (int q = 0; q < NJC; ++q) {
        const size_t base = ((size_t)q * NROWS + row) * 17;
        num += g_pout[base + c];
        den += g_pout[base + 16];
    }
    const float o = num / den;

    float m = o;
    #pragma unroll
    for (int mask = 1; mask < 16; mask <<= 1) m = fmaxf(m, __shfl_xor(m, mask, 16));
    float e = __expf(o - m), s = e;
    #pragma unroll
    for (int mask = 1; mask < 16; mask <<= 1) s += __shfl_xor(s, mask, 16);

    out[(size_t)row * HID + c] = o - m - __logf(s);
}

// ---------------------------------------------------------------------------
extern "C" void kernel_launch(void* const* d_in, const int* in_sizes, int n_in,
                              void* d_out, int out_size, void* d_ws, size_t ws_size,
                              hipStream_t stream) {
    const float* x  = (const float*)d_in[0];
    const float* W1 = (const float*)d_in[1];
    const float* b1 = (const float*)d_in[2];
    const float* W2 = (const float*)d_in[3];
    const float* b2 = (const float*)d_in[4];
    const float* W3 = (const float*)d_in[5];
    const float* b3 = (const float*)d_in[6];
    float* out = (float*)d_out;

    mlp_kernel<<<NROWS / 64, 64, 0, stream>>>(x, W1, b1, W2, b2, W3, b3);
    agg_kernel<<<dim3(NROWS / 128, NJC), 256, 0, stream>>>();
    finalize_kernel<<<(NROWS * 16) / 256, 256, 0, stream>>>(out);
}

// Round 12
// 123.114 us; speedup vs baseline: 1.0557x; 1.0557x over previous
//
#include <hip/hip_runtime.h>
#include <hip/hip_bf16.h>

#define NROWS 12288
#define NDIM  128
#define HID   16

#define NJC    16                // j-chunks (partials)
#define JSPAN  (NROWS / NJC)     // 768
#define JSTEPS (JSPAN / 32)      // 24

typedef float f32x16 __attribute__((ext_vector_type(16)));
typedef short s16x8  __attribute__((ext_vector_type(8)));

// Module-level scratch (BSS): fully rewritten every call; no d_ws dependence.
__device__ __align__(16) ushort g_hb [NROWS * HID];        // bf16 H
__device__ __align__(16) ushort g_hbs[NROWS * HID];        // bf16 (H * log2e)  (QK^T j-side)
__device__ __align__(16) ushort g_hbT[17 * NROWS];         // bf16 H^T, row 16 = ones (denominator)
__device__ float g_pout[(size_t)NJC * NROWS * 17];         // PV partials: 16 num + 1 den per row

__device__ __forceinline__ ushort f2bf(float f) {          // RNE f32->bf16
    union { float f; unsigned u; } v; v.f = f;
    unsigned r = v.u + 0x7fffu + ((v.u >> 16) & 1u);
    return (ushort)(r >> 16);
}

__device__ __forceinline__ float fast_exp2(float x) {
#if __has_builtin(__builtin_amdgcn_exp2f)
    return __builtin_amdgcn_exp2f(x);
#else
    return exp2f(x);
#endif
}

// Pack two f32 -> one uint of 2 bf16 (RNE), p0 in low half. Header
// intrinsic: compiler-visible, no inline asm.
__device__ __forceinline__ uint pack_bf16(float p0, float p1) {
    union { __hip_bfloat162 h2; uint u; } cv;
    cv.h2 = __float22bfloat162_rn(make_float2(p0, p1));
    return cv.u;
}

// Functional equivalent of v_permlane32_swap_b32(x, y): exchange x's upper
// 32 lanes with y's lower 32 lanes. Pure shfl+select, no inline asm.
// FORENSIC NOTE (r6/r7/r8/r10 failures, absmax ~0.4; r7 failed with a body
// line-identical to passing r5 — allocation context, not code shape): raw
// v_permlane32_swap/v_cvt_pk inline asm is context-fragile on this compiler.
// NEVER reintroduce inline asm for the pack/swap path.
__device__ __forceinline__ void half_swap(uint& x, uint& y, bool up) {
    const uint xs = __shfl_xor(x, 32, 64);
    const uint ys = __shfl_xor(y, 32, 64);
    const uint nx = up ? ys : x;
    const uint ny = up ? y : xs;
    x = nx; y = ny;
}

// ---------------------------------------------------------------------------
// Kernel A: MLP -> bf16 H, bf16 H*log2e, bf16 H^T (+ ones row).
// Round-9/11 version verbatim (known good).
// ---------------------------------------------------------------------------
__global__ __launch_bounds__(64) void mlp_kernel(
    const float* __restrict__ x,
    const float* __restrict__ W1, const float* __restrict__ b1,
    const float* __restrict__ W2, const float* __restrict__ b2,
    const float* __restrict__ W3, const float* __restrict__ b3)
{
    __shared__ float sW1[NDIM * HID];
    __shared__ float sW2[HID * HID];
    __shared__ float sW3[HID * HID];
    __shared__ float sb[3 * HID];

    const int t = threadIdx.x;
    for (int i = t; i < NDIM * HID; i += 64) sW1[i] = W1[i];
    for (int i = t; i < HID * HID; i += 64) { sW2[i] = W2[i]; sW3[i] = W3[i]; }
    if (t < HID) { sb[t] = b1[t]; sb[HID + t] = b2[t]; sb[2 * HID + t] = b3[t]; }
    __syncthreads();

    const int row = blockIdx.x * 64 + t;
    if (row >= NROWS) return;

    float a1[HID];
    #pragma unroll
    for (int c = 0; c < HID; ++c) a1[c] = sb[c];
    const float4* xr = reinterpret_cast<const float4*>(x + (size_t)row * NDIM);
    #pragma unroll 8
    for (int k4 = 0; k4 < NDIM / 4; ++k4) {
        float4 v = xr[k4];
        const float* w0 = &sW1[(k4 * 4 + 0) * HID];
        const float* w1 = &sW1[(k4 * 4 + 1) * HID];
        const float* w2 = &sW1[(k4 * 4 + 2) * HID];
        const float* w3 = &sW1[(k4 * 4 + 3) * HID];
        #pragma unroll
        for (int c = 0; c < HID; ++c)
            a1[c] += v.x * w0[c] + v.y * w1[c] + v.z * w2[c] + v.w * w3[c];
    }

    float a2[HID];
    #pragma unroll
    for (int c = 0; c < HID; ++c) a2[c] = sb[HID + c];
    #pragma unroll
    for (int k = 0; k < HID; ++k) {
        const float hk = a1[k];
        #pragma unroll
        for (int c = 0; c < HID; ++c) a2[c] += hk * sW2[k * HID + c];
    }

    float a3[HID];
    #pragma unroll
    for (int c = 0; c < HID; ++c) a3[c] = sb[2 * HID + c];
    #pragma unroll
    for (int k = 0; k < HID; ++k) {
        const float hk = a2[k];
        #pragma unroll
        for (int c = 0; c < HID; ++c) a3[c] += hk * sW3[k * HID + c];
    }

    ushort hb[HID], hs[HID];
    #pragma unroll
    for (int c = 0; c < HID; ++c) {
        hb[c] = f2bf(a3[c]);
        hs[c] = f2bf(a3[c] * 1.44269504088896f);   // * log2(e)
    }
    uint wb[8], ws[8];
    #pragma unroll
    for (int d = 0; d < 8; ++d) {
        wb[d] = (uint)hb[2 * d] | ((uint)hb[2 * d + 1] << 16);
        ws[d] = (uint)hs[2 * d] | ((uint)hs[2 * d + 1] << 16);
    }
    uint4* pb = reinterpret_cast<uint4*>(g_hb  + (size_t)row * HID);
    uint4* ps = reinterpret_cast<uint4*>(g_hbs + (size_t)row * HID);
    pb[0] = make_uint4(wb[0], wb[1], wb[2], wb[3]);
    pb[1] = make_uint4(wb[4], wb[5], wb[6], wb[7]);
    ps[0] = make_uint4(ws[0], ws[1], ws[2], ws[3]);
    ps[1] = make_uint4(ws[4], ws[5], ws[6], ws[7]);
    #pragma unroll
    for (int c = 0; c < HID; ++c) g_hbT[(size_t)c * NROWS + row] = hb[c];
    g_hbT[(size_t)16 * NROWS + row] = 0x3F80;      // bf16(1.0): denominator column
}

// ---------------------------------------------------------------------------
// Kernel B: MFMA flash aggregation. Round-11 body (all-intrinsic, zero
// inline asm); ONE change: j-loop unrolled x2 with two independent
// S->exp->pack streams (explicit a/b names, compile-time indices only) to
// raise per-wave ILP (r9/r11: per-SIMD issue util ~38%, latency-bound on
// the serial S-MFMA -> exp -> pack -> PV-MFMA chain; extra blocks don't
// add residency). INVARIANTS: no inline asm; no launch_bounds min-waves.
// Wave: 32 i-rows. Per 32-j tile:
//   S^T[j][i] = mfma_32x32x16(A=Hs[j-rows], B=H[i-rows], 0)   (K=HID=16)
//   p = exp2(S>0 ? S : -200)  -> pack_bf16 + half_swap -> two K=16 A-frags
//   acc = mfma(P1, HT[j..j+15], acc); acc = mfma(P2, HT[j+16..j+31], acc)
// B-side col 16 is all-ones => acc col 16 = sum_j p = denominator (free).
// ---------------------------------------------------------------------------
__global__ __launch_bounds__(256) void agg_kernel()
{
    const int lane = threadIdx.x & 63;
    const int wv   = threadIdx.x >> 6;
    const int jl   = lane & 31;       // row-in-tile for frag loads
    const int kh   = lane >> 5;       // k-half selector
    const bool up  = (lane >= 32);
    const int i0   = blockIdx.x * 128 + wv * 32;
    const int q    = blockIdx.y;
    const int jbase = q * JSPAN;

    // i-side B frag (unscaled H rows i0..i0+31), loaded once
    const s16x8 bi = *reinterpret_cast<const s16x8*>(&g_hb[((size_t)(i0 + jl)) * HID + kh * 8]);
    // PV B-side column base; cols >16 clamp to the ones-column (unused output)
    const int ccol = lane & 31;
    const ushort* tcol = &g_hbT[(size_t)(ccol < 16 ? ccol : 16) * NROWS];

    f32x16 acc, z;
    #pragma unroll
    for (int r = 0; r < 16; ++r) { acc[r] = 0.0f; z[r] = 0.0f; }

    for (int js = 0; js < JSTEPS; js += 2) {
        const int j0a = jbase + js * 32;
        const int j0b = j0a + 32;

        // both QK^T MFMAs issued up front (independent)
        const s16x8 aja = *reinterpret_cast<const s16x8*>(&g_hbs[((size_t)(j0a + jl)) * HID + kh * 8]);
        const s16x8 ajb = *reinterpret_cast<const s16x8*>(&g_hbs[((size_t)(j0b + jl)) * HID + kh * 8]);
        f32x16 Sa = __builtin_amdgcn_mfma_f32_32x32x16_bf16(aja, bi, z, 0, 0, 0);
        f32x16 Sb = __builtin_amdgcn_mfma_f32_32x32x16_bf16(ajb, bi, z, 0, 0, 0);

        float pa[16], pb[16];
        #pragma unroll
        for (int r = 0; r < 16; ++r) {
            const float sa = Sa[r];
            pa[r] = fast_exp2((sa > 0.0f) ? sa : -200.0f);   // exp2(-200)=0 => strict mask
            const float sb = Sb[r];
            pb[r] = fast_exp2((sb > 0.0f) ? sb : -200.0f);
        }

        // ---- stream a: pack + swap + 2 PV MFMAs ----
        uint a0 = pack_bf16(pa[0],  pa[1]);
        uint a1 = pack_bf16(pa[2],  pa[3]);
        uint a2 = pack_bf16(pa[4],  pa[5]);
        uint a3 = pack_bf16(pa[6],  pa[7]);
        half_swap(a0, a2, up);
        half_swap(a1, a3, up);
        uint a4 = pack_bf16(pa[8],  pa[9]);
        uint a5 = pack_bf16(pa[10], pa[11]);
        uint a6 = pack_bf16(pa[12], pa[13]);
        uint a7 = pack_bf16(pa[14], pa[15]);
        half_swap(a4, a6, up);
        half_swap(a5, a7, up);
        union { uint u[4]; s16x8 v; } A1a, A2a;
        A1a.u[0] = a0; A1a.u[1] = a1; A1a.u[2] = a2; A1a.u[3] = a3;
        A2a.u[0] = a4; A2a.u[1] = a5; A2a.u[2] = a6; A2a.u[3] = a7;
        const s16x8 b1a = *reinterpret_cast<const s16x8*>(&tcol[j0a + kh * 8]);
        const s16x8 b2a = *reinterpret_cast<const s16x8*>(&tcol[j0a + 16 + kh * 8]);
        acc = __builtin_amdgcn_mfma_f32_32x32x16_bf16(A1a.v, b1a, acc, 0, 0, 0);
        acc = __builtin_amdgcn_mfma_f32_32x32x16_bf16(A2a.v, b2a, acc, 0, 0, 0);

        // ---- stream b: pack + swap + 2 PV MFMAs ----
        uint b0 = pack_bf16(pb[0],  pb[1]);
        uint b1 = pack_bf16(pb[2],  pb[3]);
        uint b2 = pack_bf16(pb[4],  pb[5]);
        uint b3 = pack_bf16(pb[6],  pb[7]);
        half_swap(b0, b2, up);
        half_swap(b1, b3, up);
        uint b4 = pack_bf16(pb[8],  pb[9]);
        uint b5 = pack_bf16(pb[10], pb[11]);
        uint b6 = pack_bf16(pb[12], pb[13]);
        uint b7 = pack_bf16(pb[14], pb[15]);
        half_swap(b4, b6, up);
        half_swap(b5, b7, up);
        union { uint u[4]; s16x8 v; } A1b, A2b;
        A1b.u[0] = b0; A1b.u[1] = b1; A1b.u[2] = b2; A1b.u[3] = b3;
        A2b.u[0] = b4; A2b.u[1] = b5; A2b.u[2] = b6; A2b.u[3] = b7;
        const s16x8 b1f = *reinterpret_cast<const s16x8*>(&tcol[j0b + kh * 8]);
        const s16x8 b2f = *reinterpret_cast<const s16x8*>(&tcol[j0b + 16 + kh * 8]);
        acc = __builtin_amdgcn_mfma_f32_32x32x16_bf16(A1b.v, b1f, acc, 0, 0, 0);
        acc = __builtin_amdgcn_mfma_f32_32x32x16_bf16(A2b.v, b2f, acc, 0, 0, 0);
    }

    // PV output tile: col c = lane&31 (c<=16 valid incl. den), row i = (r&3)+8*(r>>2)+4*kh
    if (ccol < 17) {
        #pragma unroll
        for (int r = 0; r < 16; ++r) {
            const int il = (r & 3) + 8 * (r >> 2) + 4 * kh;
            g_pout[((size_t)q * NROWS + (i0 + il)) * 17 + ccol] = acc[r];
        }
    }
}

// ---------------------------------------------------------------------------
// Kernel C: merge partials; out = log_softmax(num/den). 16 lanes per row.
// ---------------------------------------------------------------------------
__global__ __launch_bounds__(256) void finalize_kernel(float* __restrict__ out)
{
    const int gid = blockIdx.x * 256 + threadIdx.x;
    const int row = gid >> 4;
    const int c   = gid & 15;
    if (row >= NROWS) return;

    float num = 0.0f, den = 0.0f;
    #pragma unroll
    for (int q = 0; q < NJC; ++q) {
        const size_t base = ((size_t)q * NROWS + row) * 17;
        num += g_pout[base + c];
        den += g_pout[base + 16];
    }
    const float o = num / den;

    float m = o;
    #pragma unroll
    for (int mask = 1; mask < 16; mask <<= 1) m = fmaxf(m, __shfl_xor(m, mask, 16));
    float e = __expf(o - m), s = e;
    #pragma unroll
    for (int mask = 1; mask < 16; mask <<= 1) s += __shfl_xor(s, mask, 16);

    out[(size_t)row * HID + c] = o - m - __logf(s);
}

// ---------------------------------------------------------------------------
extern "C" void kernel_launch(void* const* d_in, const int* in_sizes, int n_in,
                              void* d_out, int out_size, void* d_ws, size_t ws_size,
                              hipStream_t stream) {
    const float* x  = (const float*)d_in[0];
    const float* W1 = (const float*)d_in[1];
    const float* b1 = (const float*)d_in[2];
    const float* W2 = (const float*)d_in[3];
    const float* b2 = (const float*)d_in[4];
    const float* W3 = (const float*)d_in[5];
    const float* b3 = (const float*)d_in[6];
    float* out = (float*)d_out;

    mlp_kernel<<<NROWS / 64, 64, 0, stream>>>(x, W1, b1, W2, b2, W3, b3);
    agg_kernel<<<dim3(NROWS / 128, NJC), 256, 0, stream>>>();
    finalize_kernel<<<(NROWS * 16) / 256, 256, 0, stream>>>(out);
}